// Round 2
// baseline (584.942 us; speedup 1.0000x reference)
//
#include <hip/hip_runtime.h>
#include <stdint.h>

#define AS1 __attribute__((address_space(1)))
#define AS3 __attribute__((address_space(3)))

typedef __bf16 bf16x8 __attribute__((ext_vector_type(8)));
typedef float f32x4 __attribute__((ext_vector_type(4)));
typedef unsigned short u16;
typedef unsigned int u32;

#define LOG2E 1.4426950408889634f

// fp32 -> bf16 bits, round-to-nearest-even
__device__ __forceinline__ u16 f2b(float f) {
    u32 u = __builtin_bit_cast(u32, f);
    u = (u + 0x7fffu + ((u >> 16) & 1u)) >> 16;
    return (u16)u;
}

// async global->LDS, 16B per lane. LDS dest is wave-uniform base + lane*16.
__device__ __forceinline__ void gld16(const u16* g, u16* l) {
    __builtin_amdgcn_global_load_lds((const AS1 void*)g, (AS3 void*)l, 16, 0, 0);
}

// ---------------- fp32 -> bf16 convert (vectorized x4) ----------------
__global__ void k_cvt(const float* __restrict__ in, u16* __restrict__ out, int n4) {
    int i = blockIdx.x * 256 + threadIdx.x;
    if (i >= n4) return;
    float4 v = reinterpret_cast<const float4*>(in)[i];
    ushort4 o;
    o.x = f2b(v.x); o.y = f2b(v.y); o.z = f2b(v.z); o.w = f2b(v.w);
    reinterpret_cast<ushort4*>(out)[i] = o;
}

// ------------- transpose + convert: in [R][C] f32 -> out [C][R] bf16 -------------
__global__ void k_tr(const float* __restrict__ in, u16* __restrict__ out, int R, int C) {
    __shared__ float tl[64][65];
    int c0 = blockIdx.x * 64, r0 = blockIdx.y * 64;
    int tx = threadIdx.x & 63, ty = threadIdx.x >> 6;
#pragma unroll
    for (int i = 0; i < 16; ++i) {
        int r = i * 4 + ty;
        tl[r][tx] = in[(size_t)(r0 + r) * C + c0 + tx];
    }
    __syncthreads();
#pragma unroll
    for (int i = 0; i < 16; ++i) {
        int c = i * 4 + ty;
        out[(size_t)(c0 + c) * R + r0 + tx] = f2b(tl[tx][c]);
    }
}

// ---------------- BT-GEMM: C[M,N] = A[M,K] * BT[N,K]^T + bias ----------------
// EPI 0: gemm1 -> q/k into qk[8192][2048] bf16, v transposed into vT[b][h][dh][s] bf16
// EPI 1: gemm2 -> fp32 out[M][N]
template <int EPI>
__global__ __launch_bounds__(256, 2)
void k_gemm(const u16* __restrict__ A, const u16* __restrict__ BT,
            const float* __restrict__ bias,
            u16* __restrict__ qk, u16* __restrict__ vT,
            float* __restrict__ outf, int M, int N, int K) {
    __shared__ u16 sA[128 * 64];
    __shared__ u16 sB[128 * 64];
    const int t = threadIdx.x;
    const int lane = t & 63;
    const int w = t >> 6;
    const int lo = lane & 15, hi = lane >> 4;
    const int wr = w >> 1, wc = w & 1;
    const int m0 = blockIdx.x * 128, n0 = blockIdx.y * 128;

    // staging geometry: chunk = 1KB = 8 rows x 128B; source col pre-swizzled so that
    // LDS content at byte a = tile[a>>7][((a&127)^((row&7)<<4))>>1]
    const int srow = lane >> 3;                 // 0..7
    const int scol = ((lane & 7) ^ srow) * 8;   // bf16 element col
    const int chunk0 = w * 4;

    f32x4 acc[4][4];
#pragma unroll
    for (int i = 0; i < 4; ++i)
#pragma unroll
        for (int j = 0; j < 4; ++j) acc[i][j] = f32x4{0.f, 0.f, 0.f, 0.f};

    char* sAc = (char*)sA;
    char* sBc = (char*)sB;

    for (int kt = 0; kt < K; kt += 64) {
        const u16* Ab = A + (size_t)m0 * K + kt;
        const u16* Bb = BT + (size_t)n0 * K + kt;
#pragma unroll
        for (int c = 0; c < 4; ++c) {
            int chunk = chunk0 + c;
            int row = chunk * 8 + srow;
            gld16(Ab + (size_t)row * K + scol, (u16*)(sAc + chunk * 1024));
            gld16(Bb + (size_t)row * K + scol, (u16*)(sBc + chunk * 1024));
        }
        __syncthreads();
#pragma unroll
        for (int ks = 0; ks < 2; ++ks) {
            bf16x8 af[4], bfr[4];
#pragma unroll
            for (int mf = 0; mf < 4; ++mf) {
                int row = wr * 64 + mf * 16 + lo;
                int byte = row * 128 + (((ks * 32 + hi * 8) * 2) ^ ((row & 7) << 4));
                af[mf] = *(const bf16x8*)(sAc + byte);
            }
#pragma unroll
            for (int nf = 0; nf < 4; ++nf) {
                int row = wc * 64 + nf * 16 + lo;
                int byte = row * 128 + (((ks * 32 + hi * 8) * 2) ^ ((row & 7) << 4));
                bfr[nf] = *(const bf16x8*)(sBc + byte);
            }
#pragma unroll
            for (int mf = 0; mf < 4; ++mf)
#pragma unroll
                for (int nf = 0; nf < 4; ++nf)
                    acc[mf][nf] = __builtin_amdgcn_mfma_f32_16x16x32_bf16(
                        af[mf], bfr[nf], acc[mf][nf], 0, 0, 0);
        }
        __syncthreads();
    }

    if (EPI == 0) {
#pragma unroll
        for (int nf = 0; nf < 4; ++nf) {
            int col = n0 + wc * 64 + nf * 16 + lo;
            float bv = bias[col];
#pragma unroll
            for (int mf = 0; mf < 4; ++mf) {
                int rowb = m0 + wr * 64 + mf * 16 + hi * 4;
                if (col < 2048) {
#pragma unroll
                    for (int r = 0; r < 4; ++r)
                        qk[(size_t)(rowb + r) * 2048 + col] = f2b(acc[mf][nf][r] + bv);
                } else {
                    int hd = col - 2048;
                    int hh = hd >> 6, dh = hd & 63;
                    int bb = rowb >> 11, s = rowb & 2047;
                    size_t base = ((size_t)(bb * 16 + hh) * 64 + dh) * 2048 + s;
#pragma unroll
                    for (int r = 0; r < 4; ++r)
                        vT[base + r] = f2b(acc[mf][nf][r] + bv);
                }
            }
        }
    } else {
#pragma unroll
        for (int nf = 0; nf < 4; ++nf) {
            int col = n0 + wc * 64 + nf * 16 + lo;
            float bv = bias[col];
#pragma unroll
            for (int mf = 0; mf < 4; ++mf) {
                int rowb = m0 + wr * 64 + mf * 16 + hi * 4;
#pragma unroll
                for (int r = 0; r < 4; ++r)
                    outf[(size_t)(rowb + r) * (size_t)N + col] = acc[mf][nf][r] + bv;
            }
        }
    }
}

// ---------------- causal flash attention ----------------
// qk: [8192][2048] bf16 (q cols 0..1023, k cols 1024..2047), vT: [b][h][64][2048] bf16
// attnout: [8192][1024] bf16. Block = 4 independent waves, each owns 32 q rows.
__global__ __launch_bounds__(256, 2)
void k_attn(const u16* __restrict__ qk, const u16* __restrict__ vT,
            u16* __restrict__ attnout) {
    __shared__ u16 p_lds[4 * 32 * 128];
    const int t = threadIdx.x;
    const int lane = t & 63;
    const int w = t >> 6;
    const int lo = lane & 15, hi = lane >> 4;
    const int qt = blockIdx.x;   // 0..15
    const int h = blockIdx.y;    // 0..15
    const int b = blockIdx.z;    // 0..3
    const int bS = b * 2048;
    const int qr0 = qt * 128 + w * 32;

    // Q fragments (held in registers for the whole kernel)
    bf16x8 qf[2][2];
#pragma unroll
    for (int m = 0; m < 2; ++m)
#pragma unroll
        for (int ks = 0; ks < 2; ++ks)
            qf[m][ks] = *(const bf16x8*)(qk + (size_t)(bS + qr0 + m * 16 + lo) * 2048 +
                                         h * 64 + ks * 32 + hi * 8);

    f32x4 o[2][4];
#pragma unroll
    for (int m = 0; m < 2; ++m)
#pragma unroll
        for (int n = 0; n < 4; ++n) o[m][n] = f32x4{0.f, 0.f, 0.f, 0.f};
    float rm[2][4], rl[2][4];
#pragma unroll
    for (int m = 0; m < 2; ++m)
#pragma unroll
        for (int r = 0; r < 4; ++r) { rm[m][r] = -1e30f; rl[m][r] = 0.f; }

    char* pb = (char*)p_lds + w * (32 * 256);
    const u16* vb = vT + (size_t)(b * 16 + h) * 64 * 2048;
    const u16* kb = qk + (size_t)bS * 2048 + 1024 + h * 64;

    for (int kt = 0; kt <= qt; ++kt) {
        // ---- S = Q K^T (rows = q, cols = k-position) ----
        f32x4 sc[2][8];
#pragma unroll
        for (int m = 0; m < 2; ++m)
#pragma unroll
            for (int n = 0; n < 8; ++n) sc[m][n] = f32x4{0.f, 0.f, 0.f, 0.f};
#pragma unroll
        for (int ks = 0; ks < 2; ++ks) {
#pragma unroll
            for (int n = 0; n < 8; ++n) {
                bf16x8 kf = *(const bf16x8*)(kb + (size_t)(kt * 128 + n * 16 + lo) * 2048 +
                                             ks * 32 + hi * 8);
                sc[0][n] = __builtin_amdgcn_mfma_f32_16x16x32_bf16(qf[0][ks], kf, sc[0][n], 0, 0, 0);
                sc[1][n] = __builtin_amdgcn_mfma_f32_16x16x32_bf16(qf[1][ks], kf, sc[1][n], 0, 0, 0);
            }
        }
        const bool diag = (kt == qt);
        // ---- mask + scale ----
#pragma unroll
        for (int m = 0; m < 2; ++m) {
            int rowb = qr0 + m * 16 + hi * 4;
#pragma unroll
            for (int n = 0; n < 8; ++n) {
                int colb = kt * 128 + n * 16 + lo;
#pragma unroll
                for (int r = 0; r < 4; ++r) {
                    float v = sc[m][n][r] * 0.125f;
                    if (diag && colb > rowb + r) v = -1e30f;
                    sc[m][n][r] = v;
                }
            }
        }
        // ---- online softmax (row stats live in (hi,reg); cols across 16 lanes + n) ----
#pragma unroll
        for (int m = 0; m < 2; ++m) {
#pragma unroll
            for (int r = 0; r < 4; ++r) {
                float pm = -1e30f;
#pragma unroll
                for (int n = 0; n < 8; ++n) pm = fmaxf(pm, sc[m][n][r]);
#pragma unroll
                for (int msk = 1; msk < 16; msk <<= 1) pm = fmaxf(pm, __shfl_xor(pm, msk, 64));
                float nm = fmaxf(rm[m][r], pm);
                float f = exp2f((rm[m][r] - nm) * LOG2E);
                rm[m][r] = nm;
                float s = 0.f;
#pragma unroll
                for (int n = 0; n < 8; ++n) {
                    float p = exp2f((sc[m][n][r] - nm) * LOG2E);
                    sc[m][n][r] = p;
                    s += p;
                }
#pragma unroll
                for (int msk = 1; msk < 16; msk <<= 1) s += __shfl_xor(s, msk, 64);
                rl[m][r] = rl[m][r] * f + s;
#pragma unroll
                for (int n2 = 0; n2 < 4; ++n2) o[m][n2][r] *= f;
            }
        }
        // ---- P -> LDS (bf16, XOR-swizzled rows, per-wave private region) ----
#pragma unroll
        for (int m = 0; m < 2; ++m) {
#pragma unroll
            for (int r = 0; r < 4; ++r) {
                int row = m * 16 + hi * 4 + r;
                int rswz = (row & 7) << 4;
#pragma unroll
                for (int n = 0; n < 8; ++n) {
                    int byte = row * 256 + ((((n * 16 + lo) * 2)) ^ rswz);
                    *(u16*)(pb + byte) = f2b(sc[m][n][r]);
                }
            }
        }
        // ---- O += P * V ----
#pragma unroll
        for (int ks = 0; ks < 4; ++ks) {
            bf16x8 pa[2];
#pragma unroll
            for (int m = 0; m < 2; ++m) {
                int row = m * 16 + lo;
                int byte = row * 256 + ((ks * 64 + hi * 16) ^ ((row & 7) << 4));
                pa[m] = *(const bf16x8*)(pb + byte);
            }
#pragma unroll
            for (int n2 = 0; n2 < 4; ++n2) {
                bf16x8 vf = *(const bf16x8*)(vb + (size_t)(n2 * 16 + lo) * 2048 +
                                             kt * 128 + ks * 32 + hi * 8);
                o[0][n2] = __builtin_amdgcn_mfma_f32_16x16x32_bf16(pa[0], vf, o[0][n2], 0, 0, 0);
                o[1][n2] = __builtin_amdgcn_mfma_f32_16x16x32_bf16(pa[1], vf, o[1][n2], 0, 0, 0);
            }
        }
    }
    // ---- epilogue: normalize, store bf16 ----
#pragma unroll
    for (int m = 0; m < 2; ++m) {
#pragma unroll
        for (int r = 0; r < 4; ++r) {
            float inv = 1.0f / rl[m][r];
            int row = qr0 + m * 16 + hi * 4 + r;
#pragma unroll
            for (int n2 = 0; n2 < 4; ++n2)
                attnout[(size_t)(bS + row) * 1024 + h * 64 + n2 * 16 + lo] =
                    f2b(o[m][n2][r] * inv);
        }
    }
}

extern "C" void kernel_launch(void* const* d_in, const int* in_sizes, int n_in,
                              void* d_out, int out_size, void* d_ws, size_t ws_size,
                              hipStream_t stream) {
    const float* x     = (const float*)d_in[0];  // [4,2048,1024]
    const float* W_in  = (const float*)d_in[1];  // [1024,3072]
    const float* b_in  = (const float*)d_in[2];  // [3072]
    const float* W_out = (const float*)d_in[3];  // [1024,1024]
    const float* b_out = (const float*)d_in[4];  // [1024]
    float* out = (float*)d_out;                  // [4,2048,1024] f32

    char* ws = (char*)d_ws;
    u16* xb    = (u16*)(ws);                 // 16 MB  x bf16 [8192][1024]
    u16* winT  = (u16*)(ws + 16777216);      // 6 MB   W_in^T bf16 [3072][1024]
    u16* woutT = (u16*)(ws + 23068672);      // 2 MB   W_out^T bf16 [1024][1024]
    u16* qkb   = (u16*)(ws + 25165824);      // 32 MB  q|k bf16 [8192][2048]
    u16* vTb   = (u16*)(ws + 58720256);      // 16 MB  vT bf16 [4][16][64][2048]
    u16* attno = (u16*)(ws + 75497472);      // 16 MB  attn out bf16 [8192][1024]

    k_cvt<<<8192, 256, 0, stream>>>(x, xb, 2097152);
    k_tr<<<dim3(48, 16), 256, 0, stream>>>(W_in, winT, 1024, 3072);
    k_tr<<<dim3(16, 16), 256, 0, stream>>>(W_out, woutT, 1024, 1024);
    k_gemm<0><<<dim3(64, 24), 256, 0, stream>>>(xb, winT, b_in, qkb, vTb, nullptr,
                                                8192, 3072, 1024);
    k_attn<<<dim3(16, 16, 4), 256, 0, stream>>>(qkb, vTb, attno);
    k_gemm<1><<<dim3(64, 8), 256, 0, stream>>>(attno, woutT, b_out, nullptr, nullptr, out,
                                               8192, 1024, 1024);
}

// Round 3
// 423.743 us; speedup vs baseline: 1.3804x; 1.3804x over previous
//
#include <hip/hip_runtime.h>
#include <stdint.h>

#define AS1 __attribute__((address_space(1)))
#define AS3 __attribute__((address_space(3)))

typedef __bf16 bf16x8 __attribute__((ext_vector_type(8)));
typedef float f32x4 __attribute__((ext_vector_type(4)));
typedef unsigned short u16;
typedef unsigned int u32;

#define LOG2E 1.4426950408889634f

// fp32 -> bf16 bits, round-to-nearest-even
__device__ __forceinline__ u16 f2b(float f) {
    u32 u = __builtin_bit_cast(u32, f);
    u = (u + 0x7fffu + ((u >> 16) & 1u)) >> 16;
    return (u16)u;
}

// async global->LDS, 16B per lane. LDS dest is wave-uniform base + lane*16.
__device__ __forceinline__ void gld16(const u16* g, u16* l) {
    __builtin_amdgcn_global_load_lds((const AS1 void*)g, (AS3 void*)l, 16, 0, 0);
}

// ---------------- fp32 -> bf16 convert (vectorized x4) ----------------
__global__ void k_cvt(const float* __restrict__ in, u16* __restrict__ out, int n4) {
    int i = blockIdx.x * 256 + threadIdx.x;
    if (i >= n4) return;
    float4 v = reinterpret_cast<const float4*>(in)[i];
    ushort4 o;
    o.x = f2b(v.x); o.y = f2b(v.y); o.z = f2b(v.z); o.w = f2b(v.w);
    reinterpret_cast<ushort4*>(out)[i] = o;
}

// ------------- transpose + convert: in [R][C] f32 -> out [C][R] bf16 -------------
__global__ void k_tr(const float* __restrict__ in, u16* __restrict__ out, int R, int C) {
    __shared__ float tl[64][65];
    int c0 = blockIdx.x * 64, r0 = blockIdx.y * 64;
    int tx = threadIdx.x & 63, ty = threadIdx.x >> 6;
#pragma unroll
    for (int i = 0; i < 16; ++i) {
        int r = i * 4 + ty;
        tl[r][tx] = in[(size_t)(r0 + r) * C + c0 + tx];
    }
    __syncthreads();
#pragma unroll
    for (int i = 0; i < 16; ++i) {
        int c = i * 4 + ty;
        out[(size_t)(c0 + c) * R + r0 + tx] = f2b(tl[tx][c]);
    }
}

// ---------------- BT-GEMM: C[M,N] = A[M,K] * BT[N,K]^T + bias ----------------
// EPI 0: gemm1 -> q/k into qk[8192][2048] bf16, v transposed into vT[b][h][dh][s] bf16
// EPI 1: gemm2 -> fp32 out[M][N]
template <int EPI>
__global__ __launch_bounds__(256, 2)
void k_gemm(const u16* __restrict__ A, const u16* __restrict__ BT,
            const float* __restrict__ bias,
            u16* __restrict__ qk, u16* __restrict__ vT,
            float* __restrict__ outf, int M, int N, int K) {
    __shared__ u16 sA[128 * 64];
    __shared__ u16 sB[128 * 64];
    const int t = threadIdx.x;
    const int lane = t & 63;
    const int w = t >> 6;
    const int lo = lane & 15, hi = lane >> 4;
    const int wr = w >> 1, wc = w & 1;
    const int m0 = blockIdx.x * 128, n0 = blockIdx.y * 128;

    // staging geometry: chunk = 1KB = 8 rows x 128B; source col pre-swizzled so that
    // LDS content at byte a = tile[a>>7][((a&127)^((row&7)<<4))>>1]
    const int srow = lane >> 3;                 // 0..7
    const int scol = ((lane & 7) ^ srow) * 8;   // bf16 element col
    const int chunk0 = w * 4;

    f32x4 acc[4][4];
#pragma unroll
    for (int i = 0; i < 4; ++i)
#pragma unroll
        for (int j = 0; j < 4; ++j) acc[i][j] = f32x4{0.f, 0.f, 0.f, 0.f};

    char* sAc = (char*)sA;
    char* sBc = (char*)sB;

    for (int kt = 0; kt < K; kt += 64) {
        const u16* Ab = A + (size_t)m0 * K + kt;
        const u16* Bb = BT + (size_t)n0 * K + kt;
#pragma unroll
        for (int c = 0; c < 4; ++c) {
            int chunk = chunk0 + c;
            int row = chunk * 8 + srow;
            gld16(Ab + (size_t)row * K + scol, (u16*)(sAc + chunk * 1024));
            gld16(Bb + (size_t)row * K + scol, (u16*)(sBc + chunk * 1024));
        }
        __syncthreads();
#pragma unroll
        for (int ks = 0; ks < 2; ++ks) {
            bf16x8 af[4], bfr[4];
#pragma unroll
            for (int mf = 0; mf < 4; ++mf) {
                int row = wr * 64 + mf * 16 + lo;
                int byte = row * 128 + (((ks * 32 + hi * 8) * 2) ^ ((row & 7) << 4));
                af[mf] = *(const bf16x8*)(sAc + byte);
            }
#pragma unroll
            for (int nf = 0; nf < 4; ++nf) {
                int row = wc * 64 + nf * 16 + lo;
                int byte = row * 128 + (((ks * 32 + hi * 8) * 2) ^ ((row & 7) << 4));
                bfr[nf] = *(const bf16x8*)(sBc + byte);
            }
#pragma unroll
            for (int mf = 0; mf < 4; ++mf)
#pragma unroll
                for (int nf = 0; nf < 4; ++nf)
                    acc[mf][nf] = __builtin_amdgcn_mfma_f32_16x16x32_bf16(
                        af[mf], bfr[nf], acc[mf][nf], 0, 0, 0);
        }
        __syncthreads();
    }

    if (EPI == 0) {
#pragma unroll
        for (int nf = 0; nf < 4; ++nf) {
            int col = n0 + wc * 64 + nf * 16 + lo;
            float bv = bias[col];
#pragma unroll
            for (int mf = 0; mf < 4; ++mf) {
                int rowb = m0 + wr * 64 + mf * 16 + hi * 4;
                if (col < 2048) {
#pragma unroll
                    for (int r = 0; r < 4; ++r)
                        qk[(size_t)(rowb + r) * 2048 + col] = f2b(acc[mf][nf][r] + bv);
                } else {
                    int hd = col - 2048;
                    int hh = hd >> 6, dh = hd & 63;
                    int bb = rowb >> 11, s = rowb & 2047;
                    size_t base = ((size_t)(bb * 16 + hh) * 64 + dh) * 2048 + s;
#pragma unroll
                    for (int r = 0; r < 4; ++r)
                        vT[base + r] = f2b(acc[mf][nf][r] + bv);
                }
            }
        }
    } else {
#pragma unroll
        for (int nf = 0; nf < 4; ++nf) {
            int col = n0 + wc * 64 + nf * 16 + lo;
            float bv = bias[col];
#pragma unroll
            for (int mf = 0; mf < 4; ++mf) {
                int rowb = m0 + wr * 64 + mf * 16 + hi * 4;
#pragma unroll
                for (int r = 0; r < 4; ++r)
                    outf[(size_t)(rowb + r) * (size_t)N + col] = acc[mf][nf][r] + bv;
            }
        }
    }
}

// ---------------- causal flash attention (swapped-QK, in-register softmax) ----------------
// qk: [8192][2048] bf16 (q cols 0..1023, k cols 1024..2047), vT: [b][h][64][2048] bf16
// attnout: [8192][1024] bf16.
// 1 wave per block, 16 q-rows per task, paired tasks (j, 127-j) -> uniform 17 kt-iters.
// Scores computed transposed: sc = mfma(K,Q) -> row=k, col=q=lane&15. Softmax per-lane:
// 31 in-lane fmax/add + 2 shuffles (xor16/32). P packed via v_cvt_pk_bf16_f32 into
// XOR-swizzled LDS (8x ds_write_b64), PV as O^T = mfma(V^T, P).
__global__ __launch_bounds__(64, 4)
void k_attn(const u16* __restrict__ qk, const u16* __restrict__ vT,
            u16* __restrict__ attnout) {
    __shared__ u16 p_lds[16 * 128];   // 4 KB: P[16 q][128 k] bf16, row-XOR-swizzled
    const int lane = threadIdx.x & 63;
    const int lo = lane & 15, hi = lane >> 4;
    // bijective XCD swizzle (nwg=4096, %8==0): 64 consecutive same-XCD blocks share (b,h)
    const int orig = blockIdx.x;
    const int wgid = (orig & 7) * 512 + (orig >> 3);
    const int j0 = wgid & 63;
    const int bh = wgid >> 6;            // 0..63
    const int h = bh & 15, b = bh >> 4;
    const int bS = b * 2048;
    const u16* vb = vT + (size_t)bh * (64 * 2048);
    const u16* kb = qk + (size_t)bS * 2048 + 1024 + h * 64;
    char* pb = (char*)p_lds;
    const float C1 = 0.125f * LOG2E;     // score scale folded into log2 domain
    const int rsw = (lo & 7) << 4;       // per-row LDS XOR swizzle

#pragma unroll 1
    for (int task = 0; task < 2; ++task) {
        const int j = task ? (127 - j0) : j0;   // 16-row q tile index, 0..127
        const int qr0 = j * 16;
        const int qtile = j >> 3;               // last 128-k tile
        const int qrow = qr0 + lo;              // this lane's q row (batch-local)

        bf16x8 qf[2];
#pragma unroll
        for (int ks = 0; ks < 2; ++ks)
            qf[ks] = *(const bf16x8*)(qk + (size_t)(bS + qrow) * 2048 + h * 64 +
                                      ks * 32 + hi * 8);

        f32x4 o[4];
#pragma unroll
        for (int n2 = 0; n2 < 4; ++n2) o[n2] = f32x4{0.f, 0.f, 0.f, 0.f};
        float rm = -1e30f, rl = 0.f;

        for (int kt = 0; kt <= qtile; ++kt) {
            // ---- S^T = K Q^T : rows = k (in-lane regs), cols = q (lanes) ----
            f32x4 sc[8];
#pragma unroll
            for (int n = 0; n < 8; ++n) sc[n] = f32x4{0.f, 0.f, 0.f, 0.f};
            __builtin_amdgcn_s_setprio(1);
#pragma unroll
            for (int n = 0; n < 8; ++n) {
                const u16* kr = kb + (size_t)(kt * 128 + n * 16 + lo) * 2048;
                bf16x8 k0 = *(const bf16x8*)(kr + hi * 8);
                bf16x8 k1 = *(const bf16x8*)(kr + 32 + hi * 8);
                sc[n] = __builtin_amdgcn_mfma_f32_16x16x32_bf16(k0, qf[0], sc[n], 0, 0, 0);
                sc[n] = __builtin_amdgcn_mfma_f32_16x16x32_bf16(k1, qf[1], sc[n], 0, 0, 0);
            }
            __builtin_amdgcn_s_setprio(0);
            // ---- mask + scale (log2 domain) + per-lane max ----
            float pm = -1e30f;
            const int kb0 = kt * 128 + hi * 4;
#pragma unroll
            for (int n = 0; n < 8; ++n) {
#pragma unroll
                for (int r = 0; r < 4; ++r) {
                    float v = sc[n][r] * C1;
                    if (kb0 + n * 16 + r > qrow) v = -1e30f;  // causal mask
                    sc[n][r] = v;
                    pm = fmaxf(pm, v);
                }
            }
            // combine the 4 hi-groups sharing each q column
            pm = fmaxf(pm, __shfl_xor(pm, 16, 64));
            pm = fmaxf(pm, __shfl_xor(pm, 32, 64));
            float nm = fmaxf(rm, pm);
            float f = exp2f(rm - nm);
            rm = nm;
            float s = 0.f;
#pragma unroll
            for (int n = 0; n < 8; ++n)
#pragma unroll
                for (int r = 0; r < 4; ++r) {
                    float p = exp2f(sc[n][r] - nm);
                    sc[n][r] = p;
                    s += p;
                }
            s += __shfl_xor(s, 16, 64);
            s += __shfl_xor(s, 32, 64);
            rl = rl * f + s;
#pragma unroll
            for (int n2 = 0; n2 < 4; ++n2)
#pragma unroll
                for (int r = 0; r < 4; ++r) o[n2][r] *= f;
            // ---- P -> LDS: pack 4 bf16 (cvt_pk x2) per n, ds_write_b64, swizzled ----
#pragma unroll
            for (int n = 0; n < 8; ++n) {
                u32 w0, w1;
                asm("v_cvt_pk_bf16_f32 %0, %1, %2" : "=v"(w0) : "v"(sc[n][0]), "v"(sc[n][1]));
                asm("v_cvt_pk_bf16_f32 %0, %1, %2" : "=v"(w1) : "v"(sc[n][2]), "v"(sc[n][3]));
                uint2 pkv; pkv.x = w0; pkv.y = w1;
                *(uint2*)(pb + lo * 256 + ((n * 32 + hi * 8) ^ rsw)) = pkv;
            }
            // ---- O^T += V^T P^T : rows = d, cols = q ----
            __builtin_amdgcn_s_setprio(1);
#pragma unroll
            for (int ks = 0; ks < 4; ++ks) {
                bf16x8 pa = *(const bf16x8*)(pb + lo * 256 + ((ks * 64 + hi * 16) ^ rsw));
#pragma unroll
                for (int n2 = 0; n2 < 4; ++n2) {
                    bf16x8 vf = *(const bf16x8*)(vb + (size_t)(n2 * 16 + lo) * 2048 +
                                                 kt * 128 + ks * 32 + hi * 8);
                    o[n2] = __builtin_amdgcn_mfma_f32_16x16x32_bf16(vf, pa, o[n2], 0, 0, 0);
                }
            }
            __builtin_amdgcn_s_setprio(0);
        }
        // ---- epilogue: lane holds O^T[d = n2*16+hi*4+r][q = lo] ----
        float inv = 1.0f / rl;
#pragma unroll
        for (int n2 = 0; n2 < 4; ++n2) {
            ushort4 st;
            st.x = f2b(o[n2][0] * inv);
            st.y = f2b(o[n2][1] * inv);
            st.z = f2b(o[n2][2] * inv);
            st.w = f2b(o[n2][3] * inv);
            *(ushort4*)(attnout + (size_t)(bS + qrow) * 1024 + h * 64 + n2 * 16 + hi * 4) = st;
        }
    }
}

extern "C" void kernel_launch(void* const* d_in, const int* in_sizes, int n_in,
                              void* d_out, int out_size, void* d_ws, size_t ws_size,
                              hipStream_t stream) {
    const float* x     = (const float*)d_in[0];  // [4,2048,1024]
    const float* W_in  = (const float*)d_in[1];  // [1024,3072]
    const float* b_in  = (const float*)d_in[2];  // [3072]
    const float* W_out = (const float*)d_in[3];  // [1024,1024]
    const float* b_out = (const float*)d_in[4];  // [1024]
    float* out = (float*)d_out;                  // [4,2048,1024] f32

    char* ws = (char*)d_ws;
    u16* xb    = (u16*)(ws);                 // 16 MB  x bf16 [8192][1024]
    u16* winT  = (u16*)(ws + 16777216);      // 6 MB   W_in^T bf16 [3072][1024]
    u16* woutT = (u16*)(ws + 23068672);      // 2 MB   W_out^T bf16 [1024][1024]
    u16* qkb   = (u16*)(ws + 25165824);      // 32 MB  q|k bf16 [8192][2048]
    u16* vTb   = (u16*)(ws + 58720256);      // 16 MB  vT bf16 [4][16][64][2048]
    u16* attno = (u16*)(ws + 75497472);      // 16 MB  attn out bf16 [8192][1024]

    k_cvt<<<8192, 256, 0, stream>>>(x, xb, 2097152);
    k_tr<<<dim3(48, 16), 256, 0, stream>>>(W_in, winT, 1024, 3072);
    k_tr<<<dim3(16, 16), 256, 0, stream>>>(W_out, woutT, 1024, 1024);
    k_gemm<0><<<dim3(64, 24), 256, 0, stream>>>(xb, winT, b_in, qkb, vTb, nullptr,
                                                8192, 3072, 1024);
    k_attn<<<4096, 64, 0, stream>>>(qkb, vTb, attno);
    k_gemm<1><<<dim3(64, 8), 256, 0, stream>>>(attno, woutT, b_out, nullptr, nullptr, out,
                                               8192, 1024, 1024);
}